// Round 11
// baseline (246.752 us; speedup 1.0000x reference)
//
#include <hip/hip_runtime.h>
#include <hip/hip_bf16.h>
#include <math.h>

// Problem constants
#define B_SZ   2
#define LSEQ   1024
#define DMODEL 1024
#define DSTATE 16
#define DCONV  4
#define DINNER 2048
#define MROWS  (B_SZ * LSEQ)        // 2048
#define NCHUNK 32
#define TCHUNK (LSEQ / NCHUNK)      // 32
#define NCAT   2176                 // 2048 (W_dt) + 32 (W_x) + 96 pad
#define BKS    64                   // K-step

typedef __attribute__((ext_vector_type(8))) short bf16x8;
typedef __attribute__((ext_vector_type(4))) float f32x4;

__device__ __forceinline__ void gl2lds16(const void* g, void* l) {
    __builtin_amdgcn_global_load_lds(
        (const __attribute__((address_space(1))) void*)g,
        (__attribute__((address_space(3))) void*)l, 16, 0, 0);
}

// ------------------------- fp32 -> bf16 conversion --------------------------
__device__ __forceinline__ void cvt8(const float* __restrict__ in,
                                     __hip_bfloat16* __restrict__ out, int i)
{
    float4 a = *(const float4*)&in[i];
    float4 b = *(const float4*)&in[i + 4];
    union { __hip_bfloat16 h[8]; int4 v; } o;
    o.h[0] = __float2bfloat16(a.x); o.h[1] = __float2bfloat16(a.y);
    o.h[2] = __float2bfloat16(a.z); o.h[3] = __float2bfloat16(a.w);
    o.h[4] = __float2bfloat16(b.x); o.h[5] = __float2bfloat16(b.y);
    o.h[6] = __float2bfloat16(b.z); o.h[7] = __float2bfloat16(b.w);
    *(int4*)&out[i] = o.v;
}

__global__ __launch_bounds__(256)
void cvt_bf16(const float* __restrict__ in, __hip_bfloat16* __restrict__ out)
{
    cvt8(in, out, (blockIdx.x * 256 + threadIdx.x) * 8);
}

// two tensors in one launch (saves a launch gap)
__global__ __launch_bounds__(256)
void cvt_bf16_2(const float* __restrict__ s0, __hip_bfloat16* __restrict__ d0,
                int nb0,
                const float* __restrict__ s1, __hip_bfloat16* __restrict__ d1)
{
    const int b = blockIdx.x;
    if (b < nb0) cvt8(s0, d0, b * 2048 + threadIdx.x * 8);
    else         cvt8(s1, d1, (b - nb0) * 2048 + threadIdx.x * 8);
}

// ------------- bf16 MFMA GEMM: A via swizzled LDS, B direct from L2 ---------
// C = A @ B^T (partial over [kbase, kbase+klen)).  BM=128, BN=64, BK=64.
// 4 waves as 2x2; wave tile 64x32 = 16 MFMA/iter.
// A: staged global->LDS (gl2lds, both-sides XOR swizzle, bank-conflict-free),
//    2 buffers x 16KB, 2-phase.
// B: weights, L2-resident -> loaded straight to VGPR fragments, double-
//    buffered in registers with 1-iter prefetch (no LDS for B at all).
// IMPORTANT (round-10 lesson): the VMEM stream mixes global_load_lds and
// regular global_load — counted s_waitcnt vmcnt(N) is UNSAFE across mixed
// return paths (completion order not guaranteed). Drain vmcnt(0) before each
// barrier. The B prefetch still overlaps this iteration's LDS reads + MFMA.
// EPI 0: plain store into Cbase + blockIdx.z*pstride (split-K partials).
// EPI 2: col<DINNER -> softplus(v+bias[col]) into C; [DINNER,DINNER+32) -> C2.
template<int EPI>
__global__ __launch_bounds__(256)
void gemm_bt(const __hip_bfloat16* __restrict__ A,
             const __hip_bfloat16* __restrict__ B,
             const float* __restrict__ bias,
             float* __restrict__ Cbase, size_t pstride, int ldc,
             float* __restrict__ C2,
             int K, int klen)
{
    constexpr int SMEL = 128 * BKS;              // 8192 bf16 = 16KB per buffer
    __shared__ __hip_bfloat16 sm[2 * SMEL];

    const int tid  = threadIdx.x;
    const int lane = tid & 63;
    const int w    = tid >> 6;
    const int m0 = blockIdx.x * 128;
    const int n0 = blockIdx.y * 64;
    const int wr = w >> 1, wc = w & 1;
    const int kbase = blockIdx.z * klen;
    float* __restrict__ C = Cbase + (size_t)blockIdx.z * pstride;

    // A staging: chunk q = 8 rows x 128B; lane -> row q*8 + (lane>>3), LDS
    // slot (lane&7); source col16 pre-swizzled = (lane&7) ^ (lane>>3).
    const int lrow = lane >> 3;
    const int swcol = ((lane & 7) ^ lrow) * 8;
    const __hip_bfloat16* srcp[4];
    #pragma unroll
    for (int i = 0; i < 4; ++i) {
        const int q = w + 4 * i;                 // 0..15
        srcp[i] = A + (size_t)(m0 + q * 8 + lrow) * K + kbase + swcol;
    }

    const int l7 = lane & 7, l15 = lane & 15, lq = lane >> 4;
    const int sw0 = (lq ^ l7) * 8;               // slot holding col16 lq
    const int sw1 = sw0 ^ 32;                    // slot holding col16 lq+4

    // B fragment base pointers (per-lane, direct global)
    const __hip_bfloat16* Bp0 = B + (size_t)(n0 + wc * 32 + l15) * K + kbase + lq * 8;
    const __hip_bfloat16* Bp1 = Bp0 + (size_t)16 * K;

    f32x4 acc[4][2] = {};
    const int nt = klen / BKS;                   // even for all our shapes

    bf16x8 bA[4], bB[4];
    // prologue: stage A(0); load B(0); drain; barrier
    #pragma unroll
    for (int i = 0; i < 4; ++i)
        gl2lds16(srcp[i], sm + (w + 4 * i) * 512);
    bA[0] = *(const bf16x8*)(Bp0);
    bA[1] = *(const bf16x8*)(Bp0 + 32);
    bA[2] = *(const bf16x8*)(Bp1);
    bA[3] = *(const bf16x8*)(Bp1 + 32);
    asm volatile("s_waitcnt vmcnt(0)" ::: "memory");
    __builtin_amdgcn_s_barrier();
    __builtin_amdgcn_sched_barrier(0);

    int buf = 0;
    #define GEMM_STEP(T, BCUR, BNXT)                                          \
    {                                                                         \
        const int t_ = (T);                                                   \
        if (t_ + 1 < nt) {                                                    \
            _Pragma("unroll")                                                 \
            for (int i = 0; i < 4; ++i)                                       \
                gl2lds16(srcp[i] + (size_t)(t_ + 1) * BKS,                    \
                         sm + (buf ^ 1) * SMEL + (w + 4 * i) * 512);          \
        }                                                                     \
        const size_t ko_ = (size_t)((t_ + 1 < nt) ? t_ + 1 : t_) * BKS;       \
        BNXT[0] = *(const bf16x8*)(Bp0 + ko_);                                \
        BNXT[1] = *(const bf16x8*)(Bp0 + ko_ + 32);                           \
        BNXT[2] = *(const bf16x8*)(Bp1 + ko_);                                \
        BNXT[3] = *(const bf16x8*)(Bp1 + ko_ + 32);                           \
        const __hip_bfloat16* As_ = sm + buf * SMEL;                          \
        bf16x8 a0_[4], a1_[4];                                                \
        _Pragma("unroll")                                                     \
        for (int m = 0; m < 4; ++m) {                                         \
            const int r_ = (wr * 64 + m * 16 + l15) * BKS;                    \
            a0_[m] = *(const bf16x8*)&As_[r_ + sw0];                          \
            a1_[m] = *(const bf16x8*)&As_[r_ + sw1];                          \
        }                                                                     \
        _Pragma("unroll")                                                     \
        for (int m = 0; m < 4; ++m)                                           \
            _Pragma("unroll")                                                 \
            for (int n = 0; n < 2; ++n) {                                     \
                acc[m][n] = __builtin_amdgcn_mfma_f32_16x16x32_bf16(          \
                    a0_[m], BCUR[2 * n], acc[m][n], 0, 0, 0);                 \
                acc[m][n] = __builtin_amdgcn_mfma_f32_16x16x32_bf16(          \
                    a1_[m], BCUR[2 * n + 1], acc[m][n], 0, 0, 0);             \
            }                                                                 \
        asm volatile("s_waitcnt vmcnt(0)" ::: "memory");                      \
        __builtin_amdgcn_s_barrier();                                         \
        __builtin_amdgcn_sched_barrier(0);                                    \
        buf ^= 1;                                                             \
    }

    for (int tt = 0; tt < nt; tt += 2) {         // nt even for all our shapes
        GEMM_STEP(tt,     bA, bB);
        GEMM_STEP(tt + 1, bB, bA);
    }
    #undef GEMM_STEP

    #pragma unroll
    for (int m = 0; m < 4; ++m)
        #pragma unroll
        for (int n = 0; n < 2; ++n) {
            const int col = n0 + wc * 32 + n * 16 + l15;
            #pragma unroll
            for (int j = 0; j < 4; ++j) {
                const int row = m0 + wr * 64 + m * 16 + lq * 4 + j;
                float v = acc[m][n][j];
                if (EPI == 0) {
                    C[(size_t)row * ldc + col] = v;
                } else {  // EPI == 2: fused dt + bc epilogue
                    if (col < DINNER) {
                        v += bias[col];
                        v = (v > 20.f) ? v : log1pf(__expf(v));
                        C[(size_t)row * ldc + col] = v;
                    } else if (col < DINNER + 32) {
                        C2[(size_t)row * 32 + (col - DINNER)] = v;
                    }
                }
            }
        }
}

// ------------------ GEMM3 split-K=4 reduce: out = sum of 4 ------------------
__global__ __launch_bounds__(256)
void add4(const float* __restrict__ p, float* __restrict__ o)
{
    const size_t S = (size_t)MROWS * DMODEL;
    int i = (blockIdx.x * 256 + threadIdx.x) * 4;
    float4 a = *(const float4*)&p[i];
    float4 b = *(const float4*)&p[i + S];
    float4 c = *(const float4*)&p[i + 2 * S];
    float4 d = *(const float4*)&p[i + 3 * S];
    a.x += b.x + c.x + d.x; a.y += b.y + c.y + d.y;
    a.z += b.z + c.z + d.z; a.w += b.w + c.w + d.w;
    *(float4*)&o[i] = a;
}

// --------------- causal depthwise conv (k=4, left pad 3) + SiLU -------------
__global__ __launch_bounds__(256)
void conv_silu(const float* __restrict__ xz, const float* __restrict__ cw,
               const float* __restrict__ cb, float* __restrict__ u,
               __hip_bfloat16* __restrict__ u_bf)
{
    int idx = blockIdx.x * blockDim.x + threadIdx.x;
    int d = idx & (DINNER - 1);
    int m = idx >> 11;
    int t = m & (LSEQ - 1);
    float acc = cb[d];
    #pragma unroll
    for (int j = 0; j < DCONV; ++j) {
        int tt = t - (DCONV - 1) + j;
        if (tt >= 0)
            acc += xz[(size_t)(m - t + tt) * 4096 + d] * cw[d * DCONV + j];
    }
    float v = acc / (1.f + __expf(-acc));
    u[(size_t)m * DINNER + d] = v;
    u_bf[(size_t)m * DINNER + d] = __float2bfloat16(v);
}

// ------------------------- chunked selective scan ---------------------------
__global__ __launch_bounds__(256)
void scan_part1(const float* __restrict__ dt, const float* __restrict__ u,
                const float* __restrict__ bc, const float* __restrict__ A_log,
                float* __restrict__ s_end, float* __restrict__ dtsum)
{
    const int d = blockIdx.x * 256 + threadIdx.x;
    const int c = blockIdx.y;
    const int b = blockIdx.z;
    __shared__ float bcs[TCHUNK][32];
    {
        int f = threadIdx.x * 4;
        const float* src = bc + ((size_t)b * LSEQ + c * TCHUNK) * 32;
        *(float4*)&bcs[f >> 5][f & 31] = *(const float4*)&src[f];
    }
    float An[16];
    {
        float4 a0 = *(const float4*)&A_log[d * DSTATE + 0];
        float4 a1 = *(const float4*)&A_log[d * DSTATE + 4];
        float4 a2 = *(const float4*)&A_log[d * DSTATE + 8];
        float4 a3 = *(const float4*)&A_log[d * DSTATE + 12];
        An[0]=-__expf(a0.x); An[1]=-__expf(a0.y); An[2]=-__expf(a0.z); An[3]=-__expf(a0.w);
        An[4]=-__expf(a1.x); An[5]=-__expf(a1.y); An[6]=-__expf(a1.z); An[7]=-__expf(a1.w);
        An[8]=-__expf(a2.x); An[9]=-__expf(a2.y); An[10]=-__expf(a2.z); An[11]=-__expf(a2.w);
        An[12]=-__expf(a3.x); An[13]=-__expf(a3.y); An[14]=-__expf(a3.z); An[15]=-__expf(a3.w);
    }
    __syncthreads();
    const float* dtp = dt + ((size_t)b * LSEQ + c * TCHUNK) * DINNER + d;
    const float* up  = u  + ((size_t)b * LSEQ + c * TCHUNK) * DINNER + d;
    float s[16] = {};
    float sum = 0.f;
    for (int t = 0; t < TCHUNK; ++t) {
        float dtv = dtp[(size_t)t * DINNER];
        float uv  = up [(size_t)t * DINNER];
        sum += dtv;
        float du = dtv * uv;
        #pragma unroll
        for (int n = 0; n < 16; ++n) {
            float a = __expf(dtv * An[n]);
            s[n] = a * s[n] + du * bcs[t][n];
        }
    }
    float* se = s_end + ((size_t)(b * NCHUNK + c) * DINNER + d) * 16;
    #pragma unroll
    for (int q = 0; q < 4; ++q)
        *(float4*)&se[q * 4] = make_float4(s[q*4], s[q*4+1], s[q*4+2], s[q*4+3]);
    dtsum[(size_t)(b * NCHUNK + c) * DINNER + d] = sum;
}

// In-place combine: s_end[c] (chunk-local end state) -> state ENTERING chunk c.
__global__ __launch_bounds__(256)
void scan_combine(float* __restrict__ s_end, const float* __restrict__ dtsum,
                  const float* __restrict__ A_log)
{
    int idx = blockIdx.x * 256 + threadIdx.x;   // b*32768 + d*16 + n
    int n = idx & 15;
    int d = (idx >> 4) & (DINNER - 1);
    int b = idx >> 15;
    float An = -__expf(A_log[d * DSTATE + n]);
    float s = 0.f;
    for (int c = 0; c < NCHUNK; ++c) {
        size_t base = (size_t)(b * NCHUNK + c) * DINNER + d;
        float se = s_end[base * 16 + n];
        s_end[base * 16 + n] = s;
        float P = __expf(An * dtsum[base]);
        s = P * s + se;
    }
}

// Phase 3: local scan seeded with s_in; fuses y = sum_n s*C + D*u and the
// silu(z) gate; emits gated y as bf16.
__global__ __launch_bounds__(256)
void scan_part2(const float* __restrict__ dt, const float* __restrict__ u,
                const float* __restrict__ bc, const float* __restrict__ s_in,
                const float* __restrict__ A_log, const float* __restrict__ Dp,
                const float* __restrict__ xz, __hip_bfloat16* __restrict__ y_bf)
{
    const int d = blockIdx.x * 256 + threadIdx.x;
    const int c = blockIdx.y;
    const int b = blockIdx.z;
    __shared__ float bcs[TCHUNK][32];
    {
        int f = threadIdx.x * 4;
        const float* src = bc + ((size_t)b * LSEQ + c * TCHUNK) * 32;
        *(float4*)&bcs[f >> 5][f & 31] = *(const float4*)&src[f];
    }
    float An[16];
    {
        float4 a0 = *(const float4*)&A_log[d * DSTATE + 0];
        float4 a1 = *(const float4*)&A_log[d * DSTATE + 4];
        float4 a2 = *(const float4*)&A_log[d * DSTATE + 8];
        float4 a3 = *(const float4*)&A_log[d * DSTATE + 12];
        An[0]=-__expf(a0.x); An[1]=-__expf(a0.y); An[2]=-__expf(a0.z); An[3]=-__expf(a0.w);
        An[4]=-__expf(a1.x); An[5]=-__expf(a1.y); An[6]=-__expf(a1.z); An[7]=-__expf(a1.w);
        An[8]=-__expf(a2.x); An[9]=-__expf(a2.y); An[10]=-__expf(a2.z); An[11]=-__expf(a2.w);
        An[12]=-__expf(a3.x); An[13]=-__expf(a3.y); An[14]=-__expf(a3.z); An[15]=-__expf(a3.w);
    }
    float s[16];
    {
        const float* si = s_in + ((size_t)(b * NCHUNK + c) * DINNER + d) * 16;
        #pragma unroll
        for (int q = 0; q < 4; ++q) {
            float4 v = *(const float4*)&si[q * 4];
            s[q*4] = v.x; s[q*4+1] = v.y; s[q*4+2] = v.z; s[q*4+3] = v.w;
        }
    }
    const float Dd = Dp[d];
    __syncthreads();
    const float* dtp = dt + ((size_t)b * LSEQ + c * TCHUNK) * DINNER + d;
    const float* up  = u  + ((size_t)b * LSEQ + c * TCHUNK) * DINNER + d;
    const float* zp  = xz + ((size_t)b * LSEQ + c * TCHUNK) * 4096 + 2048 + d;
    __hip_bfloat16* yp = y_bf + ((size_t)b * LSEQ + c * TCHUNK) * DINNER + d;
    for (int t = 0; t < TCHUNK; ++t) {
        float dtv = dtp[(size_t)t * DINNER];
        float uv  = up [(size_t)t * DINNER];
        float du = dtv * uv;
        float y = Dd * uv;
        #pragma unroll
        for (int n = 0; n < 16; ++n) {
            float a = __expf(dtv * An[n]);
            s[n] = a * s[n] + du * bcs[t][n];
            y += s[n] * bcs[t][16 + n];
        }
        float zv = zp[(size_t)t * 4096];
        yp[(size_t)t * DINNER] = __float2bfloat16(y * (zv / (1.f + __expf(-zv))));
    }
}

// ---------------------------------------------------------------------------
extern "C" void kernel_launch(void* const* d_in, const int* in_sizes, int n_in,
                              void* d_out, int out_size, void* d_ws, size_t ws_size,
                              hipStream_t stream)
{
    const float* x      = (const float*)d_in[0];
    const float* W_in   = (const float*)d_in[1];
    const float* conv_w = (const float*)d_in[2];
    const float* conv_b = (const float*)d_in[3];
    const float* W_x    = (const float*)d_in[4];
    const float* W_dt   = (const float*)d_in[5];
    const float* b_dt   = (const float*)d_in[6];
    const float* A_log  = (const float*)d_in[7];
    const float* Dp     = (const float*)d_in[8];
    const float* W_out  = (const float*)d_in[9];
    float* out = (float*)d_out;

    // Workspace map — hard ceiling 94MB (95MB proven safe; 109MB overflowed).
    const size_t MB = 1ull << 20;
    char* w8 = (char*)d_ws;
    float* xz    = (float*)(w8);               // 0-32  | after scan: p3 (4x8MB)
    float* p3    = (float*)(w8);
    float* u     = (float*)(w8 + 32*MB);       // 32-48
    float* dtc   = (float*)(w8 + 48*MB);       // 48-64
    float* bc    = (float*)(w8 + 64*MB);       // 64-64.25
    float* sbuf  = (float*)(w8 + 65*MB);       // 65-73  s_end -> s_in in place
    float* dtsum = (float*)(w8 + 73*MB);       // 73-73.5
    __hip_bfloat16* u_bf   = (__hip_bfloat16*)(w8 + 74*MB); // 74-82
    // region X (82-94), time-multiplexed:
    __hip_bfloat16* x_bf   = (__hip_bfloat16*)(w8 + 82*MB); // 82-86   (GEMM1)
    __hip_bfloat16* Win_bf = (__hip_bfloat16*)(w8 + 86*MB); // 86-94   (GEMM1)
    __hip_bfloat16* Wcat_bf= (__hip_bfloat16*)(w8 + 82*MB); // 82-90.5 (GEMM2)
    __hip_bfloat16* y_bf   = (__hip_bfloat16*)(w8 + 82*MB); // 82-90 (post-GEMM2)
    __hip_bfloat16* Wout_bf= (__hip_bfloat16*)(w8 + 90*MB); // 90-94 (post-GEMM2;
                                               // overlays dead Wcat pad rows)

    // 0. convert GEMM1 inputs (one fused launch)
    cvt_bf16_2<<<1024 + 2048, 256, 0, stream>>>(x, x_bf, 1024, W_in, Win_bf);
    // 1. xz = x @ W_in.T   (M=2048, N=4096, K=1024) — 1024 blocks
    gemm_bt<0><<<dim3(16, 64, 1), 256, 0, stream>>>(
        x_bf, Win_bf, nullptr, xz, 0, 4096, nullptr, DMODEL, DMODEL);
    // 2. u = silu(causal_conv(xi) + conv_b)  (+ bf16 copy)
    conv_silu<<<(MROWS * DINNER) / 256, 256, 0, stream>>>(xz, conv_w, conv_b, u, u_bf);
    // 2b. Wcat = [W_dt; W_x] bf16 (fused; pad rows garbage — cols dropped)
    cvt_bf16_2<<<2048 + 32, 256, 0, stream>>>(W_dt, Wcat_bf, 2048,
                                              W_x, Wcat_bf + (size_t)DINNER * DINNER);
    // 3. fused GEMM2: dt = softplus(u@W_dt.T + b_dt), bc = u@W_x.T (N=2176)
    gemm_bt<2><<<dim3(16, NCAT / 64, 1), 256, 0, stream>>>(
        u_bf, Wcat_bf, b_dt, dtc, 0, DINNER, bc, DINNER, DINNER);
    // 3b. Wout bf16 (Wcat dead; 90-94 slot free)
    cvt_bf16<<<(DMODEL * DINNER) / 2048, 256, 0, stream>>>(W_out, Wout_bf);
    // 4. chunked scan (writes gated y as bf16 into region X head)
    scan_part1<<<dim3(DINNER/256, NCHUNK, B_SZ), 256, 0, stream>>>(
        dtc, u, bc, A_log, sbuf, dtsum);
    scan_combine<<<(B_SZ * DINNER * DSTATE) / 256, 256, 0, stream>>>(
        sbuf, dtsum, A_log);
    scan_part2<<<dim3(DINNER/256, NCHUNK, B_SZ), 256, 0, stream>>>(
        dtc, u, bc, sbuf, A_log, Dp, xz, y_bf);
    // 5. out = y @ W_out.T, split-K=4, partials over xz region (dead)
    gemm_bt<0><<<dim3(16, 16, 4), 256, 0, stream>>>(
        y_bf, Wout_bf, nullptr, p3, (size_t)MROWS * DMODEL, DMODEL, nullptr,
        DINNER, DINNER / 4);
    add4<<<(MROWS * DMODEL) / 1024, 256, 0, stream>>>(p3, out);
}

// Round 12
// 184.044 us; speedup vs baseline: 1.3407x; 1.3407x over previous
//
#include <hip/hip_runtime.h>
#include <hip/hip_bf16.h>
#include <math.h>

// Problem constants
#define B_SZ   2
#define LSEQ   1024
#define DMODEL 1024
#define DSTATE 16
#define DCONV  4
#define DINNER 2048
#define MROWS  (B_SZ * LSEQ)        // 2048
#define NCHUNK 32
#define TCHUNK (LSEQ / NCHUNK)      // 32
#define NCAT   2176                 // 2048 (W_dt) + 32 (W_x) + 96 pad
#define BKS    64                   // K-step

typedef __attribute__((ext_vector_type(8))) short bf16x8;
typedef __attribute__((ext_vector_type(4))) float f32x4;

__device__ __forceinline__ void gl2lds16(const void* g, void* l) {
    __builtin_amdgcn_global_load_lds(
        (const __attribute__((address_space(1))) void*)g,
        (__attribute__((address_space(3))) void*)l, 16, 0, 0);
}

// ------------------------- fp32 -> bf16 conversion --------------------------
__device__ __forceinline__ void cvt8(const float* __restrict__ in,
                                     __hip_bfloat16* __restrict__ out, int i)
{
    float4 a = *(const float4*)&in[i];
    float4 b = *(const float4*)&in[i + 4];
    union { __hip_bfloat16 h[8]; int4 v; } o;
    o.h[0] = __float2bfloat16(a.x); o.h[1] = __float2bfloat16(a.y);
    o.h[2] = __float2bfloat16(a.z); o.h[3] = __float2bfloat16(a.w);
    o.h[4] = __float2bfloat16(b.x); o.h[5] = __float2bfloat16(b.y);
    o.h[6] = __float2bfloat16(b.z); o.h[7] = __float2bfloat16(b.w);
    *(int4*)&out[i] = o.v;
}

// all five conversions (x, W_in, W_dt, W_x, W_out) in ONE launch
__global__ __launch_bounds__(256)
void cvt_all(const float* __restrict__ x,    __hip_bfloat16* __restrict__ xb,
             const float* __restrict__ win,  __hip_bfloat16* __restrict__ winb,
             const float* __restrict__ wdt,  const float* __restrict__ wx,
             __hip_bfloat16* __restrict__ wcat,
             const float* __restrict__ wout, __hip_bfloat16* __restrict__ woutb)
{
    const int b = blockIdx.x;
    const int t8 = threadIdx.x * 8;
    if      (b < 1024) cvt8(x,    xb,    b * 2048 + t8);
    else if (b < 3072) cvt8(win,  winb,  (b - 1024) * 2048 + t8);
    else if (b < 5120) cvt8(wdt,  wcat,  (b - 3072) * 2048 + t8);
    else if (b < 5152) cvt8(wx,   wcat + (size_t)DINNER * DINNER,
                                         (b - 5120) * 2048 + t8);
    else               cvt8(wout, woutb, (b - 5152) * 2048 + t8);
}

// ---------- bf16 MFMA GEMM: BM=128, BN=64, BK=64, swizzled LDS --------------
// (round-9 proven core: A+B staged via gl2lds, both-sides XOR swizzle,
//  2 buffers, drain vmcnt(0) per iter. 0 bank conflicts measured.)
// EPI 0: plain store into Cbase + blockIdx.z*pstride (split-K partials).
// EPI 2: col<DINNER -> softplus(v+bias[col]) into C; [DINNER,DINNER+32) -> C2.
template<int EPI>
__global__ __launch_bounds__(256)
void gemm_bt(const __hip_bfloat16* __restrict__ A,
             const __hip_bfloat16* __restrict__ B,
             const float* __restrict__ bias,
             float* __restrict__ Cbase, size_t pstride, int ldc,
             float* __restrict__ C2,
             int K, int klen)
{
    constexpr int BN   = 64;
    constexpr int NLD  = (128 + BN) / 8 / 4;     // 6 chunks per wave
    constexpr int SMEL = (128 + BN) * BKS;       // 12288 bf16 per buffer
    __shared__ __hip_bfloat16 sm[2 * SMEL];

    const int tid  = threadIdx.x;
    const int lane = tid & 63;
    const int w    = tid >> 6;
    const int m0 = blockIdx.x * 128;
    const int n0 = blockIdx.y * BN;
    const int wr = w >> 1, wc = w & 1;
    const int kbase = blockIdx.z * klen;
    float* __restrict__ C = Cbase + (size_t)blockIdx.z * pstride;

    // staging: chunk q = 8 rows x 128B. lane -> row q*8 + (lane>>3),
    // LDS slot (lane&7); source col16 pre-swizzled = (lane&7) ^ (lane>>3).
    const int lrow = lane >> 3;
    const int swc  = ((lane & 7) ^ lrow) * 8;    // element col in stage
    const __hip_bfloat16* srcp[NLD];
    #pragma unroll
    for (int i = 0; i < NLD; ++i) {
        const int q = w + 4 * i;                 // 0..23
        srcp[i] = (q < 16)
            ? A + (size_t)(m0 + q * 8 + lrow) * K + kbase + swc
            : B + (size_t)(n0 + (q - 16) * 8 + lrow) * K + kbase + swc;
    }

    f32x4 acc[4][2] = {};
    const int l7 = lane & 7, l15 = lane & 15, lq = lane >> 4;
    const int sw0 = (lq ^ l7) * 8;               // slot holding col16 lq
    const int sw1 = sw0 ^ 32;                    // slot holding col16 lq+4

    // prologue: stage 0 -> buf0, drain, barrier
    #pragma unroll
    for (int i = 0; i < NLD; ++i)
        gl2lds16(srcp[i], sm + (w + 4 * i) * 512);
    asm volatile("s_waitcnt vmcnt(0)" ::: "memory");
    __builtin_amdgcn_s_barrier();
    __builtin_amdgcn_sched_barrier(0);

    const int nt = klen / BKS;
    int buf = 0;
    for (int t = 0; t < nt; ++t) {
        if (t + 1 < nt) {                        // stage next early
            #pragma unroll
            for (int i = 0; i < NLD; ++i)
                gl2lds16(srcp[i] + (size_t)(t + 1) * BKS,
                         sm + (buf ^ 1) * SMEL + (w + 4 * i) * 512);
        }
        const __hip_bfloat16* As = sm + buf * SMEL;
        const __hip_bfloat16* Bs = As + 128 * BKS;
        bf16x8 a0[4], a1[4], b0[2], b1[2];
        #pragma unroll
        for (int m = 0; m < 4; ++m) {
            const int r = (wr * 64 + m * 16 + l15) * BKS;
            a0[m] = *(const bf16x8*)&As[r + sw0];
            a1[m] = *(const bf16x8*)&As[r + sw1];
        }
        #pragma unroll
        for (int n = 0; n < 2; ++n) {
            const int r = (wc * 32 + n * 16 + l15) * BKS;
            b0[n] = *(const bf16x8*)&Bs[r + sw0];
            b1[n] = *(const bf16x8*)&Bs[r + sw1];
        }
        #pragma unroll
        for (int m = 0; m < 4; ++m)
            #pragma unroll
            for (int n = 0; n < 2; ++n) {
                acc[m][n] = __builtin_amdgcn_mfma_f32_16x16x32_bf16(
                    a0[m], b0[n], acc[m][n], 0, 0, 0);
                acc[m][n] = __builtin_amdgcn_mfma_f32_16x16x32_bf16(
                    a1[m], b1[n], acc[m][n], 0, 0, 0);
            }
        asm volatile("s_waitcnt vmcnt(0)" ::: "memory");
        __builtin_amdgcn_s_barrier();
        __builtin_amdgcn_sched_barrier(0);
        buf ^= 1;
    }

    #pragma unroll
    for (int m = 0; m < 4; ++m)
        #pragma unroll
        for (int n = 0; n < 2; ++n) {
            const int col = n0 + wc * 32 + n * 16 + l15;
            #pragma unroll
            for (int j = 0; j < 4; ++j) {
                const int row = m0 + wr * 64 + m * 16 + lq * 4 + j;
                float v = acc[m][n][j];
                if (EPI == 0) {
                    C[(size_t)row * ldc + col] = v;
                } else {  // EPI == 2: fused dt + bc epilogue
                    if (col < DINNER) {
                        v += bias[col];
                        v = (v > 20.f) ? v : log1pf(__expf(v));
                        C[(size_t)row * ldc + col] = v;
                    } else if (col < DINNER + 32) {
                        C2[(size_t)row * 32 + (col - DINNER)] = v;
                    }
                }
            }
        }
}

// ------------------ GEMM3 split-K=2 reduce: out = p0 + p1 -------------------
__global__ __launch_bounds__(256)
void add2(const float* __restrict__ a, const float* __restrict__ b,
          float* __restrict__ o)
{
    int i = (blockIdx.x * 256 + threadIdx.x) * 4;
    float4 va = *(const float4*)&a[i];
    float4 vb = *(const float4*)&b[i];
    va.x += vb.x; va.y += vb.y; va.z += vb.z; va.w += vb.w;
    *(float4*)&o[i] = va;
}

// --------------- causal depthwise conv (k=4, left pad 3) + SiLU -------------
// u is kept ONLY in bf16 (saves 16MB write + 32MB of scan reads).
__global__ __launch_bounds__(256)
void conv_silu(const float* __restrict__ xz, const float* __restrict__ cw,
               const float* __restrict__ cb, __hip_bfloat16* __restrict__ u_bf)
{
    int idx = blockIdx.x * blockDim.x + threadIdx.x;
    int d = idx & (DINNER - 1);
    int m = idx >> 11;
    int t = m & (LSEQ - 1);
    float acc = cb[d];
    #pragma unroll
    for (int j = 0; j < DCONV; ++j) {
        int tt = t - (DCONV - 1) + j;
        if (tt >= 0)
            acc += xz[(size_t)(m - t + tt) * 4096 + d] * cw[d * DCONV + j];
    }
    float v = acc / (1.f + __expf(-acc));
    u_bf[(size_t)m * DINNER + d] = __float2bfloat16(v);
}

// ------------------------- chunked selective scan ---------------------------
__global__ __launch_bounds__(256)
void scan_part1(const float* __restrict__ dt, const __hip_bfloat16* __restrict__ u,
                const float* __restrict__ bc, const float* __restrict__ A_log,
                float* __restrict__ s_end, float* __restrict__ dtsum)
{
    const int d = blockIdx.x * 256 + threadIdx.x;
    const int c = blockIdx.y;
    const int b = blockIdx.z;
    __shared__ float bcs[TCHUNK][32];
    {
        int f = threadIdx.x * 4;
        const float* src = bc + ((size_t)b * LSEQ + c * TCHUNK) * 32;
        *(float4*)&bcs[f >> 5][f & 31] = *(const float4*)&src[f];
    }
    float An[16];
    {
        float4 a0 = *(const float4*)&A_log[d * DSTATE + 0];
        float4 a1 = *(const float4*)&A_log[d * DSTATE + 4];
        float4 a2 = *(const float4*)&A_log[d * DSTATE + 8];
        float4 a3 = *(const float4*)&A_log[d * DSTATE + 12];
        An[0]=-__expf(a0.x); An[1]=-__expf(a0.y); An[2]=-__expf(a0.z); An[3]=-__expf(a0.w);
        An[4]=-__expf(a1.x); An[5]=-__expf(a1.y); An[6]=-__expf(a1.z); An[7]=-__expf(a1.w);
        An[8]=-__expf(a2.x); An[9]=-__expf(a2.y); An[10]=-__expf(a2.z); An[11]=-__expf(a2.w);
        An[12]=-__expf(a3.x); An[13]=-__expf(a3.y); An[14]=-__expf(a3.z); An[15]=-__expf(a3.w);
    }
    __syncthreads();
    const float* dtp = dt + ((size_t)b * LSEQ + c * TCHUNK) * DINNER + d;
    const __hip_bfloat16* up = u + ((size_t)b * LSEQ + c * TCHUNK) * DINNER + d;
    float s[16] = {};
    float sum = 0.f;
    for (int t = 0; t < TCHUNK; ++t) {
        float dtv = dtp[(size_t)t * DINNER];
        float uv  = __bfloat162float(up[(size_t)t * DINNER]);
        sum += dtv;
        float du = dtv * uv;
        #pragma unroll
        for (int n = 0; n < 16; ++n) {
            float a = __expf(dtv * An[n]);
            s[n] = a * s[n] + du * bcs[t][n];
        }
    }
    float* se = s_end + ((size_t)(b * NCHUNK + c) * DINNER + d) * 16;
    #pragma unroll
    for (int q = 0; q < 4; ++q)
        *(float4*)&se[q * 4] = make_float4(s[q*4], s[q*4+1], s[q*4+2], s[q*4+3]);
    dtsum[(size_t)(b * NCHUNK + c) * DINNER + d] = sum;
}

// In-place combine: s_end[c] (chunk-local end state) -> state ENTERING chunk c.
__global__ __launch_bounds__(256)
void scan_combine(float* __restrict__ s_end, const float* __restrict__ dtsum,
                  const float* __restrict__ A_log)
{
    int idx = blockIdx.x * 256 + threadIdx.x;   // b*32768 + d*16 + n
    int n = idx & 15;
    int d = (idx >> 4) & (DINNER - 1);
    int b = idx >> 15;
    float An = -__expf(A_log[d * DSTATE + n]);
    float s = 0.f;
    for (int c = 0; c < NCHUNK; ++c) {
        size_t base = (size_t)(b * NCHUNK + c) * DINNER + d;
        float se = s_end[base * 16 + n];
        s_end[base * 16 + n] = s;
        float P = __expf(An * dtsum[base]);
        s = P * s + se;
    }
}

// Phase 3: local scan seeded with s_in; fuses y = sum_n s*C + D*u and the
// silu(z) gate; emits gated y as bf16.
__global__ __launch_bounds__(256)
void scan_part2(const float* __restrict__ dt, const __hip_bfloat16* __restrict__ u,
                const float* __restrict__ bc, const float* __restrict__ s_in,
                const float* __restrict__ A_log, const float* __restrict__ Dp,
                const float* __restrict__ xz, __hip_bfloat16* __restrict__ y_bf)
{
    const int d = blockIdx.x * 256 + threadIdx.x;
    const int c = blockIdx.y;
    const int b = blockIdx.z;
    __shared__ float bcs[TCHUNK][32];
    {
        int f = threadIdx.x * 4;
        const float* src = bc + ((size_t)b * LSEQ + c * TCHUNK) * 32;
        *(float4*)&bcs[f >> 5][f & 31] = *(const float4*)&src[f];
    }
    float An[16];
    {
        float4 a0 = *(const float4*)&A_log[d * DSTATE + 0];
        float4 a1 = *(const float4*)&A_log[d * DSTATE + 4];
        float4 a2 = *(const float4*)&A_log[d * DSTATE + 8];
        float4 a3 = *(const float4*)&A_log[d * DSTATE + 12];
        An[0]=-__expf(a0.x); An[1]=-__expf(a0.y); An[2]=-__expf(a0.z); An[3]=-__expf(a0.w);
        An[4]=-__expf(a1.x); An[5]=-__expf(a1.y); An[6]=-__expf(a1.z); An[7]=-__expf(a1.w);
        An[8]=-__expf(a2.x); An[9]=-__expf(a2.y); An[10]=-__expf(a2.z); An[11]=-__expf(a2.w);
        An[12]=-__expf(a3.x); An[13]=-__expf(a3.y); An[14]=-__expf(a3.z); An[15]=-__expf(a3.w);
    }
    float s[16];
    {
        const float* si = s_in + ((size_t)(b * NCHUNK + c) * DINNER + d) * 16;
        #pragma unroll
        for (int q = 0; q < 4; ++q) {
            float4 v = *(const float4*)&si[q * 4];
            s[q*4] = v.x; s[q*4+1] = v.y; s[q*4+2] = v.z; s[q*4+3] = v.w;
        }
    }
    const float Dd = Dp[d];
    __syncthreads();
    const float* dtp = dt + ((size_t)b * LSEQ + c * TCHUNK) * DINNER + d;
    const __hip_bfloat16* up = u + ((size_t)b * LSEQ + c * TCHUNK) * DINNER + d;
    const float* zp  = xz + ((size_t)b * LSEQ + c * TCHUNK) * 4096 + 2048 + d;
    __hip_bfloat16* yp = y_bf + ((size_t)b * LSEQ + c * TCHUNK) * DINNER + d;
    for (int t = 0; t < TCHUNK; ++t) {
        float dtv = dtp[(size_t)t * DINNER];
        float uv  = __bfloat162float(up[(size_t)t * DINNER]);
        float du = dtv * uv;
        float y = Dd * uv;
        #pragma unroll
        for (int n = 0; n < 16; ++n) {
            float a = __expf(dtv * An[n]);
            s[n] = a * s[n] + du * bcs[t][n];
            y += s[n] * bcs[t][16 + n];
        }
        float zv = zp[(size_t)t * 4096];
        yp[(size_t)t * DINNER] = __float2bfloat16(y * (zv / (1.f + __expf(-zv))));
    }
}

// ---------------------------------------------------------------------------
extern "C" void kernel_launch(void* const* d_in, const int* in_sizes, int n_in,
                              void* d_out, int out_size, void* d_ws, size_t ws_size,
                              hipStream_t stream)
{
    const float* x      = (const float*)d_in[0];
    const float* W_in   = (const float*)d_in[1];
    const float* conv_w = (const float*)d_in[2];
    const float* conv_b = (const float*)d_in[3];
    const float* W_x    = (const float*)d_in[4];
    const float* W_dt   = (const float*)d_in[5];
    const float* b_dt   = (const float*)d_in[6];
    const float* A_log  = (const float*)d_in[7];
    const float* Dp     = (const float*)d_in[8];
    const float* W_out  = (const float*)d_in[9];
    float* out = (float*)d_out;

    // Workspace map — 90.5MB peak (hard ceiling 94MB; 95MB proven safe,
    // 109MB overflowed in round 8). Mostly non-overlapping now:
    const size_t MB = 1ull << 20;
    char* w8 = (char*)d_ws;
    float* xz    = (float*)(w8);               // 0-32   | after scan: p3 (2x8MB)
    float* p3    = (float*)(w8);
    __hip_bfloat16* u_bf = (__hip_bfloat16*)(w8 + 32*MB);   // 32-40
    float* dtc   = (float*)(w8 + 40*MB);       // 40-56
    float* bc    = (float*)(w8 + 56*MB);       // 56-56.25
    float* sbuf  = (float*)(w8 + 57*MB);       // 57-65   s_end -> s_in in place
    float* dtsum = (float*)(w8 + 65*MB);       // 65-65.5
    __hip_bfloat16* x_bf   = (__hip_bfloat16*)(w8 + 66*MB); // 66-70  (GEMM1)
    __hip_bfloat16* Win_bf = (__hip_bfloat16*)(w8 + 70*MB); // 70-78  (GEMM1)
    __hip_bfloat16* y_bf   = (__hip_bfloat16*)(w8 + 66*MB); // 66-74  (post-GEMM1)
    __hip_bfloat16* Wcat_bf= (__hip_bfloat16*)(w8 + 78*MB); // 78-86.5
    __hip_bfloat16* Wout_bf= (__hip_bfloat16*)(w8 + 86*MB + 512*1024); // 86.5-90.5

    // 0. ALL conversions in one launch (x, W_in, W_dt, W_x, W_out)
    cvt_all<<<6176, 256, 0, stream>>>(x, x_bf, W_in, Win_bf,
                                      W_dt, W_x, Wcat_bf, W_out, Wout_bf);
    // 1. xz = x @ W_in.T   (M=2048, N=4096, K=1024) — 1024 blocks
    gemm_bt<0><<<dim3(16, 64, 1), 256, 0, stream>>>(
        x_bf, Win_bf, nullptr, xz, 0, 4096, nullptr, DMODEL, DMODEL);
    // 2. u_bf = silu(causal_conv(xi) + conv_b)
    conv_silu<<<(MROWS * DINNER) / 256, 256, 0, stream>>>(xz, conv_w, conv_b, u_bf);
    // 3. fused GEMM2: dt = softplus(u@W_dt.T + b_dt), bc = u@W_x.T (N=2176)
    gemm_bt<2><<<dim3(16, NCAT / 64, 1), 256, 0, stream>>>(
        u_bf, Wcat_bf, b_dt, dtc, 0, DINNER, bc, DINNER, DINNER);
    // 4. chunked scan (writes gated y as bf16 over dead x_bf slot)
    scan_part1<<<dim3(DINNER/256, NCHUNK, B_SZ), 256, 0, stream>>>(
        dtc, u_bf, bc, A_log, sbuf, dtsum);
    scan_combine<<<(B_SZ * DINNER * DSTATE) / 256, 256, 0, stream>>>(
        sbuf, dtsum, A_log);
    scan_part2<<<dim3(DINNER/256, NCHUNK, B_SZ), 256, 0, stream>>>(
        dtc, u_bf, bc, sbuf, A_log, Dp, xz, y_bf);
    // 5. out = y @ W_out.T, split-K=2, partials over xz region (dead)
    gemm_bt<0><<<dim3(16, 16, 2), 256, 0, stream>>>(
        y_bf, Wout_bf, nullptr, p3, (size_t)MROWS * DMODEL, DMODEL, nullptr,
        DINNER, DINNER / 2);
    add2<<<(MROWS * DMODEL) / 1024, 256, 0, stream>>>(
        p3, p3 + (size_t)MROWS * DMODEL, out);
}